// Round 2
// baseline (169.146 us; speedup 1.0000x reference)
//
#include <hip/hip_runtime.h>

typedef unsigned short u16;
typedef short bf16x8 __attribute__((ext_vector_type(8)));
typedef float f32x4 __attribute__((ext_vector_type(4)));

#define BATCH 2
#define SEQ   2048
#define CH    1024
#define NHEAD 16
#define HDIM  64
#define ROWS  (BATCH*SEQ)   // 4096

// swizzled LDS index for [*][64] bf16 tiles: breaks 128B-row bank conflicts
#define SWZ(r_, c_) (((r_)*64) + ((c_) ^ (((r_)&7)*8)))

__device__ __forceinline__ u16 f2b(float f) {
  unsigned u = __builtin_bit_cast(unsigned, f);
  u += 0x7FFFu + ((u >> 16) & 1u);
  return (u16)(u >> 16);
}
__device__ __forceinline__ float b2f(u16 h) {
  unsigned u = ((unsigned)h) << 16;
  return __builtin_bit_cast(float, u);
}

__device__ __forceinline__ void gload_lds16(const void* g, void* l) {
  __builtin_amdgcn_global_load_lds(
      (const __attribute__((address_space(1))) unsigned int*)g,
      (__attribute__((address_space(3))) unsigned int*)l, 16, 0, 0);
}

// ---------- dtype probe: flag=1 -> storage is bf16, flag=0 -> f32 ----------
__global__ void csa_detect(const u16* __restrict__ x, int* flag) {
  int t = threadIdx.x;
  bool ok = true;
  for (int i = t; i < 2048; i += 256) {
    float v = b2f(x[i]);
    ok = ok && (__builtin_fabsf(v) < 1e4f);   // NaN -> false
  }
  int wok = __all((int)ok);
  __shared__ int s[4];
  if ((t & 63) == 0) s[t >> 6] = wok;
  __syncthreads();
  if (t == 0) flag[0] = (s[0] & s[1] & s[2] & s[3]);
}

// ---------- x -> bf16 [4096][1024] ----------
__global__ void csa_convert_x(const void* __restrict__ in, u16* __restrict__ out,
                              int n8, const int* __restrict__ flagp) {
  int i = blockIdx.x * 256 + threadIdx.x;
  if (i >= n8) return;
  if (*flagp) {
    ((uint4*)out)[i] = ((const uint4*)in)[i];
  } else {
    const float4* f4 = (const float4*)in;
    float4 v0 = f4[2*i], v1 = f4[2*i+1];
    ushort4 o0, o1;
    o0.x = f2b(v0.x); o0.y = f2b(v0.y); o0.z = f2b(v0.z); o0.w = f2b(v0.w);
    o1.x = f2b(v1.x); o1.y = f2b(v1.y); o1.z = f2b(v1.z); o1.w = f2b(v1.w);
    ((ushort4*)out)[2*i]   = o0;
    ((ushort4*)out)[2*i+1] = o1;
  }
}

__global__ void csa_convert_bias(const void* __restrict__ in, float* __restrict__ out,
                                 int n, const int* __restrict__ flagp) {
  int i = blockIdx.x * 256 + threadIdx.x;
  if (i >= n) return;
  out[i] = (*flagp) ? b2f(((const u16*)in)[i]) : ((const float*)in)[i];
}

// ---------- W[R][C] -> Wt[C][R] bf16 ----------
__global__ void csa_transpose(const void* __restrict__ in, u16* __restrict__ out,
                              int R, int C, const int* __restrict__ flagp) {
  __shared__ float tile[32][33];
  const int flag = *flagp;
  const int bx = blockIdx.x * 32, by = blockIdx.y * 32;
  const int tx = threadIdx.x, ty = threadIdx.y;
  #pragma unroll
  for (int j = 0; j < 4; ++j) {
    int r = by + ty + j*8, c = bx + tx;
    float v = flag ? b2f(((const u16*)in)[(size_t)r*C + c])
                   : ((const float*)in)[(size_t)r*C + c];
    tile[ty + j*8][tx] = v;
  }
  __syncthreads();
  #pragma unroll
  for (int j = 0; j < 4; ++j) {
    int oc = bx + ty + j*8;   // column of in = row of out
    int orr = by + tx;        // row of in   = col of out
    out[(size_t)oc*R + orr] = f2b(tile[tx][ty + j*8]);
  }
}

// ---------- GEMM: C[M=4096][N] = A[M][K] * Bt[N][K]^T + bias ----------
// mode 0: scatter to q/k [bh][t][64] and v^T [bh][64][t] (N=3072)
// mode 1: write out (f32 or bf16 per flag), N=1024
__global__ __launch_bounds__(256) void csa_gemm(
    const u16* __restrict__ A, const u16* __restrict__ Bt,
    const float* __restrict__ bias, int N, int K, int mode,
    void* __restrict__ out0, u16* __restrict__ kb, u16* __restrict__ vtb,
    const int* __restrict__ flagp)
{
  __shared__ __align__(16) u16 As[128*64];
  __shared__ __align__(16) u16 Bs[128*64];
  const int t = threadIdx.x, lane = t & 63, w = t >> 6;
  const int wm = w >> 1, wn = w & 1, g = lane >> 4, qi = lane & 15;
  const int bm = blockIdx.y, bn = blockIdx.x;

  f32x4 acc[4][4] = {};

  const u16* Ab = A  + (size_t)(bm*128)*K;
  const u16* Bb = Bt + (size_t)(bn*128)*K;
  const int srow = t >> 3;          // 0..31 within a 32-row pass
  const int scol = (t & 7) * 8;

  for (int k0 = 0; k0 < K; k0 += 64) {
    #pragma unroll
    for (int p = 0; p < 4; ++p) {
      int row = p*32 + srow;
      gload_lds16(Ab + (size_t)row*K + k0 + scol, &As[p*2048 + w*512]);
      gload_lds16(Bb + (size_t)row*K + k0 + scol, &Bs[p*2048 + w*512]);
    }
    __syncthreads();
    #pragma unroll
    for (int c = 0; c < 2; ++c) {
      bf16x8 af[4], bfr[4];
      #pragma unroll
      for (int m = 0; m < 4; ++m)
        af[m] = *(const bf16x8*)&As[(wm*64 + m*16 + qi)*64 + c*32 + g*8];
      #pragma unroll
      for (int n = 0; n < 4; ++n)
        bfr[n] = *(const bf16x8*)&Bs[(wn*64 + n*16 + qi)*64 + c*32 + g*8];
      #pragma unroll
      for (int m = 0; m < 4; ++m)
        #pragma unroll
        for (int n = 0; n < 4; ++n)
          acc[m][n] = __builtin_amdgcn_mfma_f32_16x16x32_bf16(af[m], bfr[n], acc[m][n], 0, 0, 0);
    }
    __syncthreads();
  }

  if (mode == 1) {
    const int flag = *flagp;
    #pragma unroll
    for (int m = 0; m < 4; ++m) {
      const int row0 = bm*128 + wm*64 + m*16 + g*4;
      #pragma unroll
      for (int n = 0; n < 4; ++n) {
        const int col = bn*128 + wn*64 + n*16 + qi;
        const float bv = bias[col];
        if (flag) {
          u16* ob = (u16*)out0;
          #pragma unroll
          for (int r = 0; r < 4; ++r)
            ob[(size_t)(row0 + r)*N + col] = f2b(acc[m][n][r] + bv);
        } else {
          float* of = (float*)out0;
          #pragma unroll
          for (int r = 0; r < 4; ++r)
            of[(size_t)(row0 + r)*N + col] = acc[m][n][r] + bv;
        }
      }
    }
  } else {
    u16* qbo = (u16*)out0;
    #pragma unroll
    for (int m = 0; m < 4; ++m) {
      const int row0 = bm*128 + wm*64 + m*16 + g*4;
      const int bb = row0 >> 11;          // batch (no 2048-crossing: row0 % 4 == 0)
      const int t0 = row0 & 2047;
      #pragma unroll
      for (int n = 0; n < 4; ++n) {
        const int col = bn*128 + wn*64 + n*16 + qi;
        const float bv = bias[col];
        const int which = col >> 10;      // 0=q 1=k 2=v
        const int cc = col & 1023;
        const int h = cc >> 6, d = cc & 63;
        const int bh = bb*16 + h;
        if (which == 2) {
          ushort4 pw;
          pw.x = f2b(acc[m][n][0] + bv);
          pw.y = f2b(acc[m][n][1] + bv);
          pw.z = f2b(acc[m][n][2] + bv);
          pw.w = f2b(acc[m][n][3] + bv);
          *(ushort4*)&vtb[((size_t)bh*HDIM + d)*SEQ + t0] = pw;
        } else {
          u16* dst = (which == 0) ? qbo : kb;
          #pragma unroll
          for (int r = 0; r < 4; ++r)
            dst[((size_t)bh*SEQ + t0 + r)*HDIM + d] = f2b(acc[m][n][r] + bv);
        }
      }
    }
  }
}

// ---------- causal flash attention ----------
// grid: x = bh (32), y = q-tile (32); 4 waves, each owns 16 q-rows.
// swapped QK^T: st = mfma(K_frag, Q_frag) -> S^T[key][q]; P-row lane-local.
__global__ __launch_bounds__(256) void csa_attn(
    const u16* __restrict__ qb, const u16* __restrict__ kb,
    const u16* __restrict__ vtb, u16* __restrict__ yout)
{
  const int bh = blockIdx.x, qt = blockIdx.y;
  const int bidx = bh >> 4, h = bh & 15;
  const int t = threadIdx.x, lane = t & 63, w = t >> 6;
  const int g = lane >> 4, qi = lane & 15;
  __shared__ __align__(16) u16 Ks[64*64];
  __shared__ __align__(16) u16 Vs[64*64];       // V^T tile: [d][key]
  __shared__ __align__(16) u16 Ps[4][16*64];    // per-wave P [q][key]

  const int qrow = qt*64 + w*16;
  const int qglob = qrow + qi;

  bf16x8 qf[2];
  #pragma unroll
  for (int c = 0; c < 2; ++c)
    qf[c] = *(const bf16x8*)&qb[((size_t)bh*SEQ + qrow + qi)*HDIM + c*32 + g*8];

  f32x4 yacc[4] = {};
  float mrun = -1e30f, srun = 0.f;
  const int nkt = qt + 1;

  for (int kt = 0; kt < nkt; ++kt) {
    const int k0 = kt*64;
    // stage K [key][d] and V^T [d][key], swizzled
    #pragma unroll
    for (int p = 0; p < 2; ++p) {
      int cid = p*256 + t;
      int row = cid >> 3, col = (cid & 7)*8;
      uint4 kv = *(const uint4*)&kb [((size_t)bh*SEQ + k0 + row)*HDIM + col];
      uint4 vv = *(const uint4*)&vtb[((size_t)bh*HDIM + row)*SEQ + k0 + col];
      *(uint4*)&Ks[SWZ(row, col)] = kv;
      *(uint4*)&Vs[SWZ(row, col)] = vv;
    }
    __syncthreads();

    // S^T = K * Q^T  (D[key][q], key=(l>>4)*4+r within 16-subtile, q=l&15)
    f32x4 st[4] = {};
    #pragma unroll
    for (int c = 0; c < 2; ++c) {
      #pragma unroll
      for (int s4 = 0; s4 < 4; ++s4) {
        bf16x8 kf = *(const bf16x8*)&Ks[SWZ(s4*16 + qi, c*32 + g*8)];
        st[s4] = __builtin_amdgcn_mfma_f32_16x16x32_bf16(kf, qf[c], st[s4], 0, 0, 0);
      }
    }

    // scale + causal mask + online softmax (per-lane row q = qi)
    float tmax = -1e30f;
    #pragma unroll
    for (int s4 = 0; s4 < 4; ++s4)
      #pragma unroll
      for (int r = 0; r < 4; ++r) {
        int key = k0 + s4*16 + g*4 + r;
        float sv = st[s4][r] * 0.125f;
        sv = (key > qglob) ? -1e30f : sv;
        st[s4][r] = sv;
        tmax = fmaxf(tmax, sv);
      }
    tmax = fmaxf(tmax, __shfl_xor(tmax, 16));
    tmax = fmaxf(tmax, __shfl_xor(tmax, 32));
    float mnew = fmaxf(mrun, tmax);
    float tsum = 0.f;
    #pragma unroll
    for (int s4 = 0; s4 < 4; ++s4)
      #pragma unroll
      for (int r = 0; r < 4; ++r) {
        float p = __expf(st[s4][r] - mnew);
        st[s4][r] = p;
        tsum += p;
      }
    tsum += __shfl_xor(tsum, 16);
    tsum += __shfl_xor(tsum, 32);
    float fac = __expf(mrun - mnew);
    srun = srun * fac + tsum;
    mrun = mnew;

    // rescale O by the factor of each D-row's q (= g*4+r, state lives in lane g*4+r)
    #pragma unroll
    for (int r = 0; r < 4; ++r) {
      float fr = __shfl(fac, g*4 + r);
      #pragma unroll
      for (int nf = 0; nf < 4; ++nf) yacc[nf][r] *= fr;
    }

    // P -> LDS [q][key] (un-transpose via write pattern), bf16
    #pragma unroll
    for (int s4 = 0; s4 < 4; ++s4) {
      ushort4 pw;
      pw.x = f2b(st[s4][0]); pw.y = f2b(st[s4][1]);
      pw.z = f2b(st[s4][2]); pw.w = f2b(st[s4][3]);
      *(ushort4*)&Ps[w][SWZ(qi, s4*16 + g*4)] = pw;
    }
    __syncthreads();

    // O += P * V   (A=P[q][key], B=V[key][d] from V^T tile)
    #pragma unroll
    for (int c = 0; c < 2; ++c) {
      bf16x8 pa = *(const bf16x8*)&Ps[w][SWZ(qi, c*32 + g*8)];
      #pragma unroll
      for (int nf = 0; nf < 4; ++nf) {
        bf16x8 vf = *(const bf16x8*)&Vs[SWZ(nf*16 + qi, c*32 + g*8)];
        yacc[nf] = __builtin_amdgcn_mfma_f32_16x16x32_bf16(pa, vf, yacc[nf], 0, 0, 0);
      }
    }
    __syncthreads();
  }

  #pragma unroll
  for (int r = 0; r < 4; ++r) {
    float sv = __shfl(srun, g*4 + r);
    float inv = 1.f / sv;
    int qg = qrow + g*4 + r;
    #pragma unroll
    for (int nf = 0; nf < 4; ++nf) {
      int d = nf*16 + qi;
      yout[((size_t)bidx*SEQ + qg)*CH + h*HDIM + d] = f2b(yacc[nf][r] * inv);
    }
  }
}

extern "C" void kernel_launch(void* const* d_in, const int* in_sizes, int n_in,
                              void* d_out, int out_size, void* d_ws, size_t ws_size,
                              hipStream_t stream) {
  (void)in_sizes; (void)n_in; (void)out_size; (void)ws_size;
  const void* x      = d_in[0];
  const void* w_attn = d_in[1];
  const void* b_attn = d_in[2];
  const void* w_proj = d_in[3];
  const void* b_proj = d_in[4];

  char* ws = (char*)d_ws;
  const size_t MB = 1024*1024;
  int*   flag = (int*)ws;
  float* ba   = (float*)(ws + 1024);
  float* bp   = (float*)(ws + 16384);
  u16*   xb   = (u16*)(ws + 32768);              // 8 MB, reused as attention out y
  u16*   wat  = (u16*)(ws + 32768 +  8*MB);      // 6 MB  w_attn^T [3072][1024]
  u16*   wpt  = (u16*)(ws + 32768 + 14*MB);      // 2 MB  w_proj^T [1024][1024]
  u16*   qb   = (u16*)(ws + 32768 + 16*MB);      // 8 MB  [bh][t][64]
  u16*   kb   = (u16*)(ws + 32768 + 24*MB);      // 8 MB  [bh][t][64]
  u16*   vtb  = (u16*)(ws + 32768 + 32*MB);      // 8 MB  [bh][64][t]

  csa_detect<<<1, 256, 0, stream>>>((const u16*)x, flag);
  csa_convert_x<<<2048, 256, 0, stream>>>(x, xb, ROWS*CH/8, flag);
  csa_convert_bias<<<12, 256, 0, stream>>>(b_attn, ba, 3*CH, flag);
  csa_convert_bias<<<4, 256, 0, stream>>>(b_proj, bp, CH, flag);
  csa_transpose<<<dim3(96, 32), dim3(32, 8), 0, stream>>>(w_attn, wat, CH, 3*CH, flag);
  csa_transpose<<<dim3(32, 32), dim3(32, 8), 0, stream>>>(w_proj, wpt, CH, CH, flag);

  csa_gemm<<<dim3(24, 32), 256, 0, stream>>>(xb, wat, ba, 3*CH, CH, 0,
                                             qb, kb, vtb, flag);
  csa_attn<<<dim3(32, 32), 256, 0, stream>>>(qb, kb, vtb, xb);
  csa_gemm<<<dim3(8, 32), 256, 0, stream>>>(xb, wpt, bp, CH, CH, 1,
                                            d_out, nullptr, nullptr, flag);
}

// Round 3
// 149.408 us; speedup vs baseline: 1.1321x; 1.1321x over previous
//
#include <hip/hip_runtime.h>

typedef unsigned short u16;
typedef short bf16x8 __attribute__((ext_vector_type(8)));
typedef float f32x4 __attribute__((ext_vector_type(4)));

#define BATCH 2
#define SEQ   2048
#define CH    1024
#define NHEAD 16
#define HDIM  64
#define ROWS  (BATCH*SEQ)   // 4096

// swizzled LDS index for [*][64] bf16 tiles: breaks 128B-row bank conflicts
#define SWZ(r_, c_) (((r_)*64) + ((c_) ^ (((r_)&7)*8)))

__device__ __forceinline__ u16 f2b(float f) {
  unsigned u = __builtin_bit_cast(unsigned, f);
  u += 0x7FFFu + ((u >> 16) & 1u);
  return (u16)(u >> 16);
}
__device__ __forceinline__ float b2f(u16 h) {
  unsigned u = ((unsigned)h) << 16;
  return __builtin_bit_cast(float, u);
}
__device__ __forceinline__ float exp2_fast(float x) {
  float r; asm("v_exp_f32 %0, %1" : "=v"(r) : "v"(x)); return r;
}
__device__ __forceinline__ unsigned cvt_pk_bf16(float a, float b) {
  unsigned r; asm("v_cvt_pk_bf16_f32 %0, %1, %2" : "=v"(r) : "v"(a), "v"(b)); return r;
}

__device__ __forceinline__ void gload_lds16(const void* g, void* l) {
  __builtin_amdgcn_global_load_lds(
      (const __attribute__((address_space(1))) unsigned int*)g,
      (__attribute__((address_space(3))) unsigned int*)l, 16, 0, 0);
}

// ---------- dtype probe: flag=1 -> storage is bf16, flag=0 -> f32 ----------
__global__ void csa_detect(const u16* __restrict__ x, int* flag) {
  int t = threadIdx.x;
  bool ok = true;
  for (int i = t; i < 2048; i += 256) {
    float v = b2f(x[i]);
    ok = ok && (__builtin_fabsf(v) < 1e4f);   // NaN -> false
  }
  int wok = __all((int)ok);
  __shared__ int s[4];
  if ((t & 63) == 0) s[t >> 6] = wok;
  __syncthreads();
  if (t == 0) flag[0] = (s[0] & s[1] & s[2] & s[3]);
}

// ---------- x -> bf16 [4096][1024] ----------
__global__ void csa_convert_x(const void* __restrict__ in, u16* __restrict__ out,
                              int n8, const int* __restrict__ flagp) {
  int i = blockIdx.x * 256 + threadIdx.x;
  if (i >= n8) return;
  if (*flagp) {
    ((uint4*)out)[i] = ((const uint4*)in)[i];
  } else {
    const float4* f4 = (const float4*)in;
    float4 v0 = f4[2*i], v1 = f4[2*i+1];
    ushort4 o0, o1;
    o0.x = f2b(v0.x); o0.y = f2b(v0.y); o0.z = f2b(v0.z); o0.w = f2b(v0.w);
    o1.x = f2b(v1.x); o1.y = f2b(v1.y); o1.z = f2b(v1.z); o1.w = f2b(v1.w);
    ((ushort4*)out)[2*i]   = o0;
    ((ushort4*)out)[2*i+1] = o1;
  }
}

__global__ void csa_convert_bias(const void* __restrict__ in, float* __restrict__ out,
                                 int n, const int* __restrict__ flagp) {
  int i = blockIdx.x * 256 + threadIdx.x;
  if (i >= n) return;
  out[i] = (*flagp) ? b2f(((const u16*)in)[i]) : ((const float*)in)[i];
}

// ---------- W[R][C] -> Wt[C][R] bf16 ----------
__global__ void csa_transpose(const void* __restrict__ in, u16* __restrict__ out,
                              int R, int C, const int* __restrict__ flagp) {
  __shared__ float tile[32][33];
  const int flag = *flagp;
  const int bx = blockIdx.x * 32, by = blockIdx.y * 32;
  const int tx = threadIdx.x, ty = threadIdx.y;
  #pragma unroll
  for (int j = 0; j < 4; ++j) {
    int r = by + ty + j*8, c = bx + tx;
    float v = flag ? b2f(((const u16*)in)[(size_t)r*C + c])
                   : ((const float*)in)[(size_t)r*C + c];
    tile[ty + j*8][tx] = v;
  }
  __syncthreads();
  #pragma unroll
  for (int j = 0; j < 4; ++j) {
    int oc = bx + ty + j*8;   // column of in = row of out
    int orr = by + tx;        // row of in   = col of out
    out[(size_t)oc*R + orr] = f2b(tile[tx][ty + j*8]);
  }
}

// ---------- GEMM: C[M=4096][N] = A[M][K] * Bt[N][K]^T + bias ----------
__global__ __launch_bounds__(256) void csa_gemm(
    const u16* __restrict__ A, const u16* __restrict__ Bt,
    const float* __restrict__ bias, int N, int K, int mode,
    void* __restrict__ out0, u16* __restrict__ kb, u16* __restrict__ vtb,
    const int* __restrict__ flagp)
{
  __shared__ __align__(16) u16 As[128*64];
  __shared__ __align__(16) u16 Bs[128*64];
  const int t = threadIdx.x, lane = t & 63, w = t >> 6;
  const int wm = w >> 1, wn = w & 1, g = lane >> 4, qi = lane & 15;
  const int bm = blockIdx.y, bn = blockIdx.x;

  f32x4 acc[4][4] = {};

  const u16* Ab = A  + (size_t)(bm*128)*K;
  const u16* Bb = Bt + (size_t)(bn*128)*K;
  const int srow = t >> 3;          // 0..31 within a 32-row pass
  const int scol = (t & 7) * 8;

  for (int k0 = 0; k0 < K; k0 += 64) {
    #pragma unroll
    for (int p = 0; p < 4; ++p) {
      int row = p*32 + srow;
      gload_lds16(Ab + (size_t)row*K + k0 + scol, &As[p*2048 + w*512]);
      gload_lds16(Bb + (size_t)row*K + k0 + scol, &Bs[p*2048 + w*512]);
    }
    __syncthreads();
    #pragma unroll
    for (int c = 0; c < 2; ++c) {
      bf16x8 af[4], bfr[4];
      #pragma unroll
      for (int m = 0; m < 4; ++m)
        af[m] = *(const bf16x8*)&As[(wm*64 + m*16 + qi)*64 + c*32 + g*8];
      #pragma unroll
      for (int n = 0; n < 4; ++n)
        bfr[n] = *(const bf16x8*)&Bs[(wn*64 + n*16 + qi)*64 + c*32 + g*8];
      #pragma unroll
      for (int m = 0; m < 4; ++m)
        #pragma unroll
        for (int n = 0; n < 4; ++n)
          acc[m][n] = __builtin_amdgcn_mfma_f32_16x16x32_bf16(af[m], bfr[n], acc[m][n], 0, 0, 0);
    }
    __syncthreads();
  }

  if (mode == 1) {
    const int flag = *flagp;
    #pragma unroll
    for (int m = 0; m < 4; ++m) {
      const int row0 = bm*128 + wm*64 + m*16 + g*4;
      #pragma unroll
      for (int n = 0; n < 4; ++n) {
        const int col = bn*128 + wn*64 + n*16 + qi;
        const float bv = bias[col];
        if (flag) {
          u16* ob = (u16*)out0;
          #pragma unroll
          for (int r = 0; r < 4; ++r)
            ob[(size_t)(row0 + r)*N + col] = f2b(acc[m][n][r] + bv);
        } else {
          float* of = (float*)out0;
          #pragma unroll
          for (int r = 0; r < 4; ++r)
            of[(size_t)(row0 + r)*N + col] = acc[m][n][r] + bv;
        }
      }
    }
  } else {
    u16* qbo = (u16*)out0;
    #pragma unroll
    for (int m = 0; m < 4; ++m) {
      const int row0 = bm*128 + wm*64 + m*16 + g*4;
      const int bb = row0 >> 11;          // batch (no 2048-crossing: row0 % 4 == 0)
      const int t0 = row0 & 2047;
      #pragma unroll
      for (int n = 0; n < 4; ++n) {
        const int col = bn*128 + wn*64 + n*16 + qi;
        const float bv = bias[col];
        const int which = col >> 10;      // 0=q 1=k 2=v
        const int cc = col & 1023;
        const int h = cc >> 6, d = cc & 63;
        const int bh = bb*16 + h;
        if (which == 2) {
          ushort4 pw;
          pw.x = f2b(acc[m][n][0] + bv);
          pw.y = f2b(acc[m][n][1] + bv);
          pw.z = f2b(acc[m][n][2] + bv);
          pw.w = f2b(acc[m][n][3] + bv);
          *(ushort4*)&vtb[((size_t)bh*HDIM + d)*SEQ + t0] = pw;
        } else {
          u16* dst = (which == 0) ? qbo : kb;
          #pragma unroll
          for (int r = 0; r < 4; ++r)
            dst[((size_t)bh*SEQ + t0 + r)*HDIM + d] = f2b(acc[m][n][r] + bv);
        }
      }
    }
  }
}

// ---------- causal flash attention v2 ----------
// grid: x = bh (32), y = pair (16). Block processes q-tiles {p, 31-p}: every
// block does exactly 33 kt-iterations (load balance). Double-buffered K/V with
// single-barrier prefetch schedule; staging = global_load_lds w/ pre-swizzled
// per-lane source + linear LDS dest (swizzle is an XOR involution).
// Swapped QK^T (mfma(K,Q)) -> S^T[key][q]; exp2-domain softmax, scale folded
// into Q; diagonal-only masking; defer-max rescale (THR=11.5 in log2 domain).
__global__ __launch_bounds__(256) void csa_attn(
    const u16* __restrict__ qb, const u16* __restrict__ kb,
    const u16* __restrict__ vtb, u16* __restrict__ yout)
{
  const int bh = blockIdx.x, pair = blockIdx.y;
  const int bidx = bh >> 4, h = bh & 15;
  const int t = threadIdx.x, lane = t & 63, w = t >> 6;
  const int g = lane >> 4, qi = lane & 15;
  __shared__ __align__(16) u16 Ks[2][64*64];
  __shared__ __align__(16) u16 Vs[2][64*64];    // V^T tile: [d][key]
  __shared__ __align__(16) u16 Ps[4][16*64];    // per-wave P [q][key] (no barrier)

  const size_t kvbase = (size_t)bh * SEQ * HDIM;   // == bh*HDIM*SEQ for vtb
  const int srow = t >> 3;            // 0..31 within a 32-row pass
  const int ssw  = ((t >> 3) & 7) * 8;
  const int scol = ((t & 7) * 8) ^ ssw;  // pre-swizzled source column

  // loop-invariant LDS element offsets
  int offK[2][4], offPw[4], offPr[2];
  #pragma unroll
  for (int c = 0; c < 2; ++c) {
    offPr[c] = SWZ(qi, c*32 + g*8);
    #pragma unroll
    for (int s4 = 0; s4 < 4; ++s4) offK[c][s4] = SWZ(s4*16 + qi, c*32 + g*8);
  }
  #pragma unroll
  for (int s4 = 0; s4 < 4; ++s4) offPw[s4] = SWZ(qi, s4*16 + g*4);

  const float QSCALE = 0.18033688011112042f;   // 0.125 * log2(e)
  const int lq = w*16 + qi;                    // local q row within 64-tile

  for (int half = 0; half < 2; ++half) {
    const int qt = half ? (31 - pair) : pair;
    const int qrow = qt*64 + w*16;
    const int nkt = qt + 1;

    // Q fragment, pre-scaled by 0.125*log2e (exp2-domain softmax)
    bf16x8 qf[2];
    #pragma unroll
    for (int c = 0; c < 2; ++c) {
      qf[c] = *(const bf16x8*)&qb[(kvbase + (size_t)(qrow + qi)*HDIM) + c*32 + g*8];
      #pragma unroll
      for (int e = 0; e < 8; ++e)
        qf[c][e] = (short)f2b(b2f((u16)qf[c][e]) * QSCALE);
    }

    f32x4 yacc[4] = {};
    float mrun = -1e30f, srun = 0.f;

    // prologue: stage kt=0 into buf 0
    #pragma unroll
    for (int p = 0; p < 2; ++p) {
      int row = p*32 + srow;
      gload_lds16(kb  + kvbase + (size_t)row*HDIM + scol,      &Ks[0][p*2048 + w*512]);
      gload_lds16(vtb + kvbase + (size_t)row*SEQ  + scol,      &Vs[0][p*2048 + w*512]);
    }
    __syncthreads();

    int cur = 0;
    for (int kt = 0; kt < nkt; ++kt) {
      // prefetch kt+1 into buf^1 (flies under compute; drained at barrier)
      if (kt + 1 < nkt) {
        const int k1 = (kt + 1) * 64;
        #pragma unroll
        for (int p = 0; p < 2; ++p) {
          int row = p*32 + srow;
          gload_lds16(kb  + kvbase + (size_t)(k1 + row)*HDIM + scol, &Ks[cur^1][p*2048 + w*512]);
          gload_lds16(vtb + kvbase + (size_t)row*SEQ + k1 + scol,    &Vs[cur^1][p*2048 + w*512]);
        }
      }

      // S^T = K * Q^T
      f32x4 st[4] = {};
      #pragma unroll
      for (int c = 0; c < 2; ++c)
        #pragma unroll
        for (int s4 = 0; s4 < 4; ++s4) {
          bf16x8 kf = *(const bf16x8*)&Ks[cur][offK[c][s4]];
          st[s4] = __builtin_amdgcn_mfma_f32_16x16x32_bf16(kf, qf[c], st[s4], 0, 0, 0);
        }

      // diagonal-only causal mask
      if (kt == nkt - 1) {
        #pragma unroll
        for (int s4 = 0; s4 < 4; ++s4)
          #pragma unroll
          for (int r = 0; r < 4; ++r)
            if (s4*16 + g*4 + r > lq) st[s4][r] = -3.0e38f;
      }

      // online softmax (exp2 domain), defer-max
      float tmax = st[0][0];
      #pragma unroll
      for (int s4 = 0; s4 < 4; ++s4)
        #pragma unroll
        for (int r = 0; r < 4; ++r) tmax = fmaxf(tmax, st[s4][r]);
      tmax = fmaxf(tmax, __shfl_xor(tmax, 16));
      tmax = fmaxf(tmax, __shfl_xor(tmax, 32));
      if (!__all(tmax - mrun <= 11.5f)) {
        float mnew = fmaxf(mrun, tmax);
        float fac = exp2_fast(mrun - mnew);
        #pragma unroll
        for (int r = 0; r < 4; ++r) {
          float fr = __shfl(fac, g*4 + r);
          #pragma unroll
          for (int nf = 0; nf < 4; ++nf) yacc[nf][r] *= fr;
        }
        srun *= fac;
        mrun = mnew;
      }
      float tsum = 0.f;
      #pragma unroll
      for (int s4 = 0; s4 < 4; ++s4)
        #pragma unroll
        for (int r = 0; r < 4; ++r) {
          float pv = exp2_fast(st[s4][r] - mrun);
          st[s4][r] = pv;
          tsum += pv;
        }
      tsum += __shfl_xor(tsum, 16);
      tsum += __shfl_xor(tsum, 32);
      srun += tsum;

      // P -> per-wave LDS (bf16 via cvt_pk; same-wave, no barrier)
      #pragma unroll
      for (int s4 = 0; s4 < 4; ++s4) {
        uint2 pw;
        pw.x = cvt_pk_bf16(st[s4][0], st[s4][1]);
        pw.y = cvt_pk_bf16(st[s4][2], st[s4][3]);
        *(uint2*)&Ps[w][offPw[s4]] = pw;
      }

      // O += P * V
      #pragma unroll
      for (int c = 0; c < 2; ++c) {
        bf16x8 pa = *(const bf16x8*)&Ps[w][offPr[c]];
        #pragma unroll
        for (int nf = 0; nf < 4; ++nf) {
          bf16x8 vf = *(const bf16x8*)&Vs[cur][offK[c][nf]];
          yacc[nf] = __builtin_amdgcn_mfma_f32_16x16x32_bf16(pa, vf, yacc[nf], 0, 0, 0);
        }
      }

      __syncthreads();   // drains prefetch (vmcnt) + guards buf reuse
      cur ^= 1;
    }

    // epilogue for this tile
    #pragma unroll
    for (int r = 0; r < 4; ++r) {
      float sv = __shfl(srun, g*4 + r);
      float inv = 1.f / sv;
      int qg = qrow + g*4 + r;
      #pragma unroll
      for (int nf = 0; nf < 4; ++nf) {
        int d = nf*16 + qi;
        yout[((size_t)bidx*SEQ + qg)*CH + h*HDIM + d] = f2b(yacc[nf][r] * inv);
      }
    }
  }
}

extern "C" void kernel_launch(void* const* d_in, const int* in_sizes, int n_in,
                              void* d_out, int out_size, void* d_ws, size_t ws_size,
                              hipStream_t stream) {
  (void)in_sizes; (void)n_in; (void)out_size; (void)ws_size;
  const void* x      = d_in[0];
  const void* w_attn = d_in[1];
  const void* b_attn = d_in[2];
  const void* w_proj = d_in[3];
  const void* b_proj = d_in[4];

  char* ws = (char*)d_ws;
  const size_t MB = 1024*1024;
  int*   flag = (int*)ws;
  float* ba   = (float*)(ws + 1024);
  float* bp   = (float*)(ws + 16384);
  u16*   xb   = (u16*)(ws + 32768);              // 8 MB, reused as attention out y
  u16*   wat  = (u16*)(ws + 32768 +  8*MB);      // 6 MB  w_attn^T [3072][1024]
  u16*   wpt  = (u16*)(ws + 32768 + 14*MB);      // 2 MB  w_proj^T [1024][1024]
  u16*   qb   = (u16*)(ws + 32768 + 16*MB);      // 8 MB  [bh][t][64]
  u16*   kb   = (u16*)(ws + 32768 + 24*MB);      // 8 MB  [bh][t][64]
  u16*   vtb  = (u16*)(ws + 32768 + 32*MB);      // 8 MB  [bh][64][t]

  csa_detect<<<1, 256, 0, stream>>>((const u16*)x, flag);
  csa_convert_x<<<2048, 256, 0, stream>>>(x, xb, ROWS*CH/8, flag);
  csa_convert_bias<<<12, 256, 0, stream>>>(b_attn, ba, 3*CH, flag);
  csa_convert_bias<<<4, 256, 0, stream>>>(b_proj, bp, CH, flag);
  csa_transpose<<<dim3(96, 32), dim3(32, 8), 0, stream>>>(w_attn, wat, CH, 3*CH, flag);
  csa_transpose<<<dim3(32, 32), dim3(32, 8), 0, stream>>>(w_proj, wpt, CH, CH, flag);

  csa_gemm<<<dim3(24, 32), 256, 0, stream>>>(xb, wat, ba, 3*CH, CH, 0,
                                             qb, kb, vtb, flag);
  csa_attn<<<dim3(32, 16), 256, 0, stream>>>(qb, kb, vtb, xb);
  csa_gemm<<<dim3(8, 32), 256, 0, stream>>>(xb, wpt, bp, CH, CH, 1,
                                            d_out, nullptr, nullptr, flag);
}